// Round 4
// baseline (595.497 us; speedup 1.0000x reference)
//
#include <hip/hip_runtime.h>
#include <float.h>

#define NTOK 32768  // 16 * 2048 tokens per modality

// ws layout (float-element offsets)
#define WS_W2   0        // 1280 floats of np-replica ||w||^2
#define WS_X2   2048     // 5 * NTOK floats of np-replica ||x||^2
#define WS_CNT  165888   // 5 ints (ambiguous counters)
#define WS_LIST 166144   // 5 * NTOK ints (ambiguous token lists)

// ================= numpy pairwise-sum replica (fp32, PW_BLOCKSIZE=128) ======
__device__ __forceinline__ float pw_sq_block_g(const float* __restrict__ a, int n) {
    float r[8];
    #pragma unroll
    for (int j = 0; j < 8; ++j) r[j] = __fmul_rn(a[j], a[j]);
    for (int i = 8; i < n; i += 8)
        #pragma unroll
        for (int j = 0; j < 8; ++j)
            r[j] = __fadd_rn(r[j], __fmul_rn(a[i + j], a[i + j]));
    return __fadd_rn(__fadd_rn(__fadd_rn(r[0], r[1]), __fadd_rn(r[2], r[3])),
                     __fadd_rn(__fadd_rn(r[4], r[5]), __fadd_rn(r[6], r[7])));
}

template <int STRIDE>
__device__ __forceinline__ float pw_sq_block_s(const float* a, int n) {
    float r[8];
    #pragma unroll
    for (int j = 0; j < 8; ++j) { float v = a[j * STRIDE]; r[j] = __fmul_rn(v, v); }
    for (int i = 8; i < n; i += 8)
        #pragma unroll
        for (int j = 0; j < 8; ++j) {
            float v = a[(i + j) * STRIDE];
            r[j] = __fadd_rn(r[j], __fmul_rn(v, v));
        }
    return __fadd_rn(__fadd_rn(__fadd_rn(r[0], r[1]), __fadd_rn(r[2], r[3])),
                     __fadd_rn(__fadd_rn(r[4], r[5]), __fadd_rn(r[6], r[7])));
}

__global__ void w2_kernel(const float* __restrict__ W, float* __restrict__ w2,
                          int K, int D) {
    int k = blockIdx.x * blockDim.x + threadIdx.x;
    if (k >= K) return;
    const float* row = W + (size_t)k * D;
    float s = (D > 128)
        ? __fadd_rn(pw_sq_block_g(row, 128), pw_sq_block_g(row + 128, D - 128))
        : pw_sq_block_g(row, D);
    w2[k] = s;
}

// ---- fused fp32-screen GEMM + top2 argmin + gather + loss ----
template <int D, int K, int TOK, int TX, int DC>
__global__ __launch_bounds__(256)
void vq_kernel(const float* __restrict__ X, const float* __restrict__ W,
               const float* __restrict__ w2, float* __restrict__ q_out,
               float* __restrict__ idx_out, float* __restrict__ loss_out,
               float* __restrict__ x2_save, int* __restrict__ amb_cnt,
               int* __restrict__ amb_list, float inv_nd, float margin)
{
    constexpr int TY  = 256 / TX;     // code groups (8 codes each)
    constexpr int KC  = TY * 8;       // codes per K-chunk
    constexpr int TPT = TOK / TX;     // tokens per thread (4)
    constexpr int XST = TOK + 4;
    constexpr int WST = KC + 4;
    constexpr int NKC = K / KC;
    constexpr int NDC = D / DC;

    __shared__ float Xs[D][XST];      // X transposed [d][t]
    __shared__ union {
        float ws[DC][WST];            // W chunk transposed [d][k]
        struct { float b1v[TY][TOK]; int b1i[TY][TOK]; float b2v[TY][TOK]; } red;
    } U;
    __shared__ float x2s[TOK];
    __shared__ int   idx_s[TOK];
    __shared__ float lred[4];

    const int tid = threadIdx.x;
    const int tx  = tid % TX;
    const int ty  = tid / TX;
    const int t0  = blockIdx.x * TOK;

    // ---- stage X transposed, t-fastest lanes (conflict-free LDS writes) ----
    for (int i = tid; i < TOK * (D / 4); i += 256) {
        int t  = i % TOK;
        int d4 = i / TOK;
        const float4 v = *reinterpret_cast<const float4*>(
            X + (size_t)(t0 + t) * D + d4 * 4);
        Xs[d4 * 4 + 0][t] = v.x;
        Xs[d4 * 4 + 1][t] = v.y;
        Xs[d4 * 4 + 2][t] = v.z;
        Xs[d4 * 4 + 3][t] = v.w;
    }
    __syncthreads();

    // ---- numpy-pairwise ||x||^2 (exact np.sum(x*x,1) replica) ----
    if (tid < TOK) {
        const float* col = &Xs[0][tid];
        float s = (D > 128)
            ? __fadd_rn(pw_sq_block_s<XST>(col, 128),
                        pw_sq_block_s<XST>(col + 128 * XST, D - 128))
            : pw_sq_block_s<XST>(col, D);
        x2s[tid] = s;
        x2_save[t0 + tid] = s;
    }

    // ---- screen GEMM with per-thread running top-2 ----
    float b1v[TPT], b2v[TPT];
    int   b1i[TPT];
    #pragma unroll
    for (int ii = 0; ii < TPT; ++ii) { b1v[ii] = FLT_MAX; b2v[ii] = FLT_MAX; b1i[ii] = 0; }

    for (int kc = 0; kc < NKC; ++kc) {
        float acc[TPT][8];
        #pragma unroll
        for (int ii = 0; ii < TPT; ++ii)
            #pragma unroll
            for (int j = 0; j < 8; ++j) acc[ii][j] = 0.f;

        for (int dc = 0; dc < NDC; ++dc) {
            __syncthreads();
            // stage W chunk transposed, k-fastest lanes (conflict-free writes)
            for (int i = tid; i < KC * (DC / 4); i += 256) {
                int k  = i % KC;
                int d4 = i / KC;
                const float4 v = *reinterpret_cast<const float4*>(
                    W + (size_t)(kc * KC + k) * D + dc * DC + d4 * 4);
                U.ws[d4 * 4 + 0][k] = v.x;
                U.ws[d4 * 4 + 1][k] = v.y;
                U.ws[d4 * 4 + 2][k] = v.z;
                U.ws[d4 * 4 + 3][k] = v.w;
            }
            __syncthreads();
            #pragma unroll
            for (int d = 0; d < DC; ++d) {
                const float4 xv = *reinterpret_cast<const float4*>(&Xs[dc * DC + d][tx * TPT]);
                const float4 wa = *reinterpret_cast<const float4*>(&U.ws[d][ty * 8]);
                const float4 wb = *reinterpret_cast<const float4*>(&U.ws[d][ty * 8 + 4]);
                const float xr[4] = {xv.x, xv.y, xv.z, xv.w};
                const float wr[8] = {wa.x, wa.y, wa.z, wa.w, wb.x, wb.y, wb.z, wb.w};
                #pragma unroll
                for (int ii = 0; ii < TPT; ++ii)
                    #pragma unroll
                    for (int j = 0; j < 8; ++j)
                        acc[ii][j] = fmaf(xr[ii], wr[j], acc[ii][j]);
            }
        }
        // fold into running top-2 (k ascending within thread: kc asc, j asc)
        const int kbase = kc * KC + ty * 8;
        #pragma unroll
        for (int ii = 0; ii < TPT; ++ii)
            #pragma unroll
            for (int j = 0; j < 8; ++j) {
                float s = fmaf(-2.f, acc[ii][j], w2[kbase + j]);
                if (s < b1v[ii]) { b2v[ii] = b1v[ii]; b1v[ii] = s; b1i[ii] = kbase + j; }
                else if (s < b2v[ii]) b2v[ii] = s;
            }
    }

    __syncthreads();                  // all GEMM reads of U.ws complete
    #pragma unroll
    for (int ii = 0; ii < TPT; ++ii) {
        U.red.b1v[ty][tx * TPT + ii] = b1v[ii];
        U.red.b1i[ty][tx * TPT + ii] = b1i[ii];
        U.red.b2v[ty][tx * TPT + ii] = b2v[ii];
    }
    __syncthreads();

    if (tid < TOK) {
        float B1 = FLT_MAX, B2 = FLT_MAX; int BI = 0;
        for (int r = 0; r < TY; ++r) {
            float v1 = U.red.b1v[r][tid];
            float v2 = U.red.b2v[r][tid];
            int   i1 = U.red.b1i[r][tid];
            if (v1 < B1) { B2 = B1; B1 = v1; BI = i1; }
            else if (v1 < B2) B2 = v1;
            if (v2 < B2) B2 = v2;
        }
        idx_s[tid] = BI;
        idx_out[t0 + tid] = (float)BI;
        if (B2 - B1 <= margin) {       // near-tie: exact rescore later
            int p = atomicAdd(amb_cnt, 1);
            amb_list[p] = t0 + tid;
        }
    }
    __syncthreads();

    // ---- gather q = W[idx] + commitment-loss partial (t-fastest) ----
    float lp = 0.f;
    for (int i = tid; i < TOK * (D / 4); i += 256) {
        int t  = i % TOK;
        int d4 = i / TOK;
        int k  = idx_s[t];
        const float4 w = *reinterpret_cast<const float4*>(W + (size_t)k * D + d4 * 4);
        float xa = Xs[d4 * 4 + 0][t], xb = Xs[d4 * 4 + 1][t];
        float xc = Xs[d4 * 4 + 2][t], xd = Xs[d4 * 4 + 3][t];
        *reinterpret_cast<float4*>(q_out + (size_t)(t0 + t) * D + d4 * 4) = w;
        float dx;
        dx = w.x - xa; lp = fmaf(dx, dx, lp);
        dx = w.y - xb; lp = fmaf(dx, dx, lp);
        dx = w.z - xc; lp = fmaf(dx, dx, lp);
        dx = w.w - xd; lp = fmaf(dx, dx, lp);
    }
    #pragma unroll
    for (int off = 32; off > 0; off >>= 1) lp += __shfl_down(lp, off, 64);
    if ((tid & 63) == 0) lred[tid >> 6] = lp;
    __syncthreads();
    if (tid == 0) {
        float tot = (lred[0] + lred[1]) + (lred[2] + lred[3]);
        atomicAdd(loss_out, tot * inv_nd);
    }
}

// ---- exact f64 rescore of ambiguous tokens: full K scan, np-replica fp32 d ----
template <int D, int K>
__global__ __launch_bounds__(256)
void cleanup_kernel(const float* __restrict__ X, const float* __restrict__ W,
                    const float* __restrict__ w2, const float* __restrict__ x2,
                    float* __restrict__ q_out, float* __restrict__ idx_out,
                    float* __restrict__ loss_out,
                    const int* __restrict__ cnt, const int* __restrict__ list,
                    float inv_nd)
{
    constexpr int CPL = K / 64;       // codes per lane
    const int n    = *cnt;
    const int gw   = (blockIdx.x * 256 + threadIdx.x) >> 6;
    const int lane = threadIdx.x & 63;
    const int nw   = (gridDim.x * 256) >> 6;

    for (int e = gw; e < n; e += nw) {
        const int t = list[e];
        const float* xr = X + (size_t)t * D;
        double acc[CPL];
        #pragma unroll
        for (int c = 0; c < CPL; ++c) {
            const float* wr = W + (size_t)(lane + (c << 6)) * D;
            double a = 0.0;
            for (int d4 = 0; d4 < D / 4; ++d4) {
                const float4 wv = *reinterpret_cast<const float4*>(wr + d4 * 4);
                const float4 xv = *reinterpret_cast<const float4*>(xr + d4 * 4);
                a = fma((double)xv.x, (double)wv.x, a);
                a = fma((double)xv.y, (double)wv.y, a);
                a = fma((double)xv.z, (double)wv.z, a);
                a = fma((double)xv.w, (double)wv.w, a);
            }
            acc[c] = a;
        }
        const float x2t = x2[t];
        float bv = FLT_MAX; int bk = 0x7fffffff;
        #pragma unroll
        for (int c = 0; c < CPL; ++c) {
            const int k = lane + (c << 6);
            const float m = (float)acc[c];                   // fl32(dot)
            const float s = __fsub_rn(__fadd_rn(x2t, w2[k]), __fmul_rn(2.0f, m));
            if (s < bv || (s == bv && k < bk)) { bv = s; bk = k; }
        }
        for (int off = 32; off; off >>= 1) {
            const float ov = __shfl_down(bv, off, 64);
            const int   ok = __shfl_down(bk, off, 64);
            if (ov < bv || (ov == bv && ok < bk)) { bv = ov; bk = ok; }
        }
        bk = __shfl(bk, 0, 64);
        const int oldk = (int)idx_out[t];
        if (bk != oldk) {
            if (lane == 0) idx_out[t] = (float)bk;
            const float* wn = W + (size_t)bk * D;
            const float* wo = W + (size_t)oldk * D;
            float dl = 0.f;
            for (int d = lane; d < D; d += 64) {
                const float xv = xr[d], a = wn[d], b = wo[d];
                q_out[(size_t)t * D + d] = a;
                const float da = a - xv, db = b - xv;
                dl += da * da - db * db;
            }
            for (int off = 32; off; off >>= 1) dl += __shfl_down(dl, off, 64);
            if (lane == 0) atomicAdd(loss_out, dl * inv_nd);
        }
    }
}

extern "C" void kernel_launch(void* const* d_in, const int* in_sizes, int n_in,
                              void* d_out, int out_size, void* d_ws, size_t ws_size,
                              hipStream_t stream)
{
    const float* x_hand = (const float*)d_in[0];
    const float* W_hand = (const float*)d_in[1];
    const float* x_loc  = (const float*)d_in[2];
    const float* W_loc  = (const float*)d_in[3];
    const float* x_ori  = (const float*)d_in[4];
    const float* W_ori  = (const float*)d_in[5];
    const float* x_mov  = (const float*)d_in[6];
    const float* W_mov  = (const float*)d_in[7];
    const float* x_nmf  = (const float*)d_in[8];
    const float* W_nmf  = (const float*)d_in[9];

    float* out = (float*)d_out;
    float* q_hand = out;
    float* q_loc  = out + 8388608;
    float* q_ori  = out + 12582912;
    float* q_mov  = out + 14680064;
    float* q_nmf  = out + 18874368;
    float* i_hand = out + 20971520;
    float* i_loc  = out + 21004288;
    float* i_ori  = out + 21037056;
    float* i_mov  = out + 21069824;
    float* i_nmf  = out + 21102592;
    float* loss   = out + 21135360;

    float* wsf = (float*)d_ws;
    float* w2b  = wsf + WS_W2;
    float* w2_hand = w2b, *w2_loc = w2b + 512, *w2_ori = w2b + 768,
         * w2_mov = w2b + 896, *w2_nmf = w2b + 1152;
    float* x2b  = wsf + WS_X2;
    int*   cnt  = (int*)(wsf + WS_CNT);
    int*   lst  = (int*)(wsf + WS_LIST);

    hipMemsetAsync(loss, 0, sizeof(float), stream);
    hipMemsetAsync(cnt, 0, 5 * sizeof(int), stream);

    w2_kernel<<<2, 256, 0, stream>>>(W_hand, w2_hand, 512, 256);
    w2_kernel<<<1, 256, 0, stream>>>(W_loc,  w2_loc,  256, 128);
    w2_kernel<<<1, 256, 0, stream>>>(W_ori,  w2_ori,  128, 64);
    w2_kernel<<<1, 256, 0, stream>>>(W_mov,  w2_mov,  256, 128);
    w2_kernel<<<1, 256, 0, stream>>>(W_nmf,  w2_nmf,  128, 64);

    // margin = D * 4e-7 (covers 2 ulp(x2-scale) np roundings + fp32 dot err, 1.5x slack)
    vq_kernel<256, 512, 32, 8, 16><<<NTOK / 32, 256, 0, stream>>>(
        x_hand, W_hand, w2_hand, q_hand, i_hand, loss,
        x2b + 0 * NTOK, cnt + 0, lst + 0 * NTOK,
        1.0f / (32768.0f * 256.0f), 256 * 4e-7f);
    cleanup_kernel<256, 512><<<64, 256, 0, stream>>>(
        x_hand, W_hand, w2_hand, x2b + 0 * NTOK, q_hand, i_hand, loss,
        cnt + 0, lst + 0 * NTOK, 1.0f / (32768.0f * 256.0f));

    vq_kernel<128, 256, 64, 16, 32><<<NTOK / 64, 256, 0, stream>>>(
        x_loc, W_loc, w2_loc, q_loc, i_loc, loss,
        x2b + 1 * NTOK, cnt + 1, lst + 1 * NTOK,
        1.0f / (32768.0f * 128.0f), 128 * 4e-7f);
    cleanup_kernel<128, 256><<<64, 256, 0, stream>>>(
        x_loc, W_loc, w2_loc, x2b + 1 * NTOK, q_loc, i_loc, loss,
        cnt + 1, lst + 1 * NTOK, 1.0f / (32768.0f * 128.0f));

    vq_kernel<64, 128, 64, 16, 32><<<NTOK / 64, 256, 0, stream>>>(
        x_ori, W_ori, w2_ori, q_ori, i_ori, loss,
        x2b + 2 * NTOK, cnt + 2, lst + 2 * NTOK,
        1.0f / (32768.0f * 64.0f), 64 * 4e-7f);
    cleanup_kernel<64, 128><<<64, 256, 0, stream>>>(
        x_ori, W_ori, w2_ori, x2b + 2 * NTOK, q_ori, i_ori, loss,
        cnt + 2, lst + 2 * NTOK, 1.0f / (32768.0f * 64.0f));

    vq_kernel<128, 256, 64, 16, 32><<<NTOK / 64, 256, 0, stream>>>(
        x_mov, W_mov, w2_mov, q_mov, i_mov, loss,
        x2b + 3 * NTOK, cnt + 3, lst + 3 * NTOK,
        1.0f / (32768.0f * 128.0f), 128 * 4e-7f);
    cleanup_kernel<128, 256><<<64, 256, 0, stream>>>(
        x_mov, W_mov, w2_mov, x2b + 3 * NTOK, q_mov, i_mov, loss,
        cnt + 3, lst + 3 * NTOK, 1.0f / (32768.0f * 128.0f));

    vq_kernel<64, 128, 64, 16, 32><<<NTOK / 64, 256, 0, stream>>>(
        x_nmf, W_nmf, w2_nmf, q_nmf, i_nmf, loss,
        x2b + 4 * NTOK, cnt + 4, lst + 4 * NTOK,
        1.0f / (32768.0f * 64.0f), 64 * 4e-7f);
    cleanup_kernel<64, 128><<<64, 256, 0, stream>>>(
        x_nmf, W_nmf, w2_nmf, x2b + 4 * NTOK, q_nmf, i_nmf, loss,
        cnt + 4, lst + 4 * NTOK, 1.0f / (32768.0f * 64.0f));
}

// Round 5
// 416.223 us; speedup vs baseline: 1.4307x; 1.4307x over previous
//
#include <hip/hip_runtime.h>
#include <float.h>

#define NTOK 32768  // 16 * 2048 tokens per modality

typedef __attribute__((ext_vector_type(8))) short bf16x8;
typedef __attribute__((ext_vector_type(4))) float f32x4;

// ---- ws byte layout ----
#define WSB_W2    0          // 1280 floats
#define WSB_X2    8192       // 5*NTOK floats (655360 B)
#define WSB_CNT   663808     // 5 ints
#define WSB_LIST  664064     // 5*NTOK ints (655360 B)
#define WSB_WSP   1572864    // swizzled bf16 hi/lo planes (852 KB)

#define GLOAD16(g, l)                                                        \
  __builtin_amdgcn_global_load_lds(                                          \
      (__attribute__((address_space(1))) const void*)(const void*)(g),       \
      (__attribute__((address_space(3))) void*)(void*)(l), 16, 0, 0)

__device__ __forceinline__ unsigned short f2bf(float f) {
    unsigned u = __float_as_uint(f);
    return (unsigned short)((u + 0x7FFFu + ((u >> 16) & 1u)) >> 16);
}
__device__ __forceinline__ float bf2f(unsigned short h) {
    return __uint_as_float(((unsigned)h) << 16);
}

// ================= numpy pairwise-sum replica (fp32) for ||w||^2 ============
__device__ __forceinline__ float pw_sq_block_g(const float* __restrict__ a, int n) {
    float r[8];
    #pragma unroll
    for (int j = 0; j < 8; ++j) r[j] = __fmul_rn(a[j], a[j]);
    for (int i = 8; i < n; i += 8)
        #pragma unroll
        for (int j = 0; j < 8; ++j)
            r[j] = __fadd_rn(r[j], __fmul_rn(a[i + j], a[i + j]));
    return __fadd_rn(__fadd_rn(__fadd_rn(r[0], r[1]), __fadd_rn(r[2], r[3])),
                     __fadd_rn(__fadd_rn(r[4], r[5]), __fadd_rn(r[6], r[7])));
}

__global__ void w2_kernel(const float* __restrict__ W, float* __restrict__ w2,
                          int K, int D) {
    int k = blockIdx.x * blockDim.x + threadIdx.x;
    if (k >= K) return;
    const float* row = W + (size_t)k * D;
    float s = (D > 128)
        ? __fadd_rn(pw_sq_block_g(row, 128), pw_sq_block_g(row + 128, D - 128))
        : pw_sq_block_g(row, D);
    w2[k] = s;
}

// ---- split W into bf16 hi/lo planes, pre-swizzled per 16-code tile ----
__global__ void wsplit_kernel(const float* __restrict__ W,
                              unsigned char* __restrict__ dst, int K, int D) {
    int i = blockIdx.x * 256 + threadIdx.x;  // element-pair index
    if (i >= K * D / 2) return;
    int k  = i / (D / 2);
    int d2 = i % (D / 2);
    float2 v = *(const float2*)(W + (size_t)k * D + 2 * d2);
    unsigned short h0 = f2bf(v.x), h1 = f2bf(v.y);
    unsigned short l0 = f2bf(__fsub_rn(v.x, bf2f(h0)));
    unsigned short l1 = f2bf(__fsub_rn(v.y, bf2f(h1)));
    int tileb = 16 * D * 2;
    int o  = (k & 15) * (D * 2) + d2 * 4;
    int os = o ^ ((k & 7) << 4);             // XOR swizzle (read side matches)
    size_t tb = (size_t)(k >> 4) * (2 * (size_t)tileb);
    *(unsigned int*)(dst + tb + os)         = (unsigned)h0 | ((unsigned)h1 << 16);
    *(unsigned int*)(dst + tb + tileb + os) = (unsigned)l0 | ((unsigned)l1 << 16);
}

// ---- MFMA bf16-split screen: top-2 argmin + gather + loss ----
template <int D, int K>
__global__ __launch_bounds__(256)
void vq_mfma(const float* __restrict__ X, const float* __restrict__ W,
             const unsigned char* __restrict__ Wsp, const float* __restrict__ w2,
             float* __restrict__ q_out, float* __restrict__ idx_out,
             float* __restrict__ loss_out, float* __restrict__ x2_save,
             int* __restrict__ amb_cnt, int* __restrict__ amb_list,
             float inv_nd, float margin)
{
    constexpr int DS    = D / 32;       // MFMA K-steps
    constexpr int NT    = K / 16;       // code tiles
    constexpr int TILEB = 16 * D * 2;   // bytes per plane-tile
    constexpr int STG   = (2 * TILEB) / 4096;  // gload16 iters (256 thr)

    __shared__ __align__(16) unsigned char lds[2 * 2 * TILEB];  // [buf][plane]
    __shared__ int   idx_s[64];
    __shared__ float lred[4];

    const int tid  = threadIdx.x;
    const int lane = tid & 63;
    const int wv   = tid >> 6;
    const int t0   = blockIdx.x * 64;
    const int tw   = t0 + wv * 16 + (lane & 15);   // this lane's token

    // ---- phase 0: numpy-pairwise ||x||^2 (exact replica, lane-split tree) ----
    {
        const float* xr = X + (size_t)tw * D;
        const int jg = lane >> 4;                  // j-pair group 0..3
        constexpr int B1M = (D > 128) ? 16 : (D / 8);
        float2 v = *(const float2*)(xr + 2 * jg);
        float r0 = __fmul_rn(v.x, v.x), r1 = __fmul_rn(v.y, v.y);
        #pragma unroll
        for (int m = 1; m < B1M; ++m) {
            float2 u = *(const float2*)(xr + 8 * m + 2 * jg);
            r0 = __fadd_rn(r0, __fmul_rn(u.x, u.x));
            r1 = __fadd_rn(r1, __fmul_rn(u.y, u.y));
        }
        float p = __fadd_rn(r0, r1);               // r[2jg]+r[2jg+1]
        p = __fadd_rn(p, __shfl_xor(p, 16, 64));   // (r0+r1)+(r2+r3) | (r4..r7)
        p = __fadd_rn(p, __shfl_xor(p, 32, 64));   // full np combine tree
        float x2v = p;
        if (D > 128) {                             // second 128-block (D=256)
            float2 w0 = *(const float2*)(xr + 128 + 2 * jg);
            float s0 = __fmul_rn(w0.x, w0.x), s1 = __fmul_rn(w0.y, w0.y);
            #pragma unroll
            for (int m = 1; m < 16; ++m) {
                float2 u = *(const float2*)(xr + 128 + 8 * m + 2 * jg);
                s0 = __fadd_rn(s0, __fmul_rn(u.x, u.x));
                s1 = __fadd_rn(s1, __fmul_rn(u.y, u.y));
            }
            float q2 = __fadd_rn(s0, s1);
            q2 = __fadd_rn(q2, __shfl_xor(q2, 16, 64));
            q2 = __fadd_rn(q2, __shfl_xor(q2, 32, 64));
            x2v = __fadd_rn(p, q2);
        }
        if ((lane >> 4) == 0) x2_save[tw] = x2v;
    }

    // ---- phase 1: X B-fragments (bf16 hi/lo) into registers ----
    bf16x8 bhi[DS], blo[DS];
    {
        const float* xr = X + (size_t)tw * D + (lane >> 4) * 8;
        #pragma unroll
        for (int ds = 0; ds < DS; ++ds) {
            float4 a = *(const float4*)(xr + ds * 32);
            float4 b = *(const float4*)(xr + ds * 32 + 4);
            float f[8] = {a.x, a.y, a.z, a.w, b.x, b.y, b.z, b.w};
            bf16x8 h, l;
            #pragma unroll
            for (int j = 0; j < 8; ++j) {
                unsigned short hh = f2bf(f[j]);
                h[j] = (short)hh;
                l[j] = (short)f2bf(__fsub_rn(f[j], bf2f(hh)));
            }
            bhi[ds] = h; blo[ds] = l;
        }
    }

    // ---- phase 2: k-loop, double-buffered W tiles, 3-way split MFMA ----
    float b1v = FLT_MAX, b2v = FLT_MAX;
    int   b1i = 0;
    {
        const int row   = lane & 15;               // code within tile
        const int g     = lane >> 4;
        const int abase = row * (D * 2);
        const int sw    = (row & 7) << 4;
        #pragma unroll
        for (int s = 0; s < STG; ++s)
            GLOAD16(Wsp + tid * 16 + s * 4096, lds + tid * 16 + s * 4096);
        __syncthreads();

        for (int kt = 0; kt < NT; ++kt) {
            const int cur = kt & 1;
            if (kt + 1 < NT) {                     // prefetch next tile
                const unsigned char* src = Wsp + (size_t)(kt + 1) * (2 * TILEB);
                unsigned char* dl = lds + (cur ^ 1) * (2 * TILEB);
                #pragma unroll
                for (int s = 0; s < STG; ++s)
                    GLOAD16(src + tid * 16 + s * 4096, dl + tid * 16 + s * 4096);
            }
            const unsigned char* base = lds + cur * (2 * TILEB);
            f32x4 acc0 = {0.f, 0.f, 0.f, 0.f}, acc1 = {0.f, 0.f, 0.f, 0.f};
            #pragma unroll
            for (int ds = 0; ds < DS; ++ds) {
                const int off = (abase + ds * 64 + g * 16) ^ sw;
                bf16x8 ahi = *(const bf16x8*)(base + off);
                bf16x8 alo = *(const bf16x8*)(base + TILEB + off);
                if (ds & 1) {                      // two independent acc chains
                    acc1 = __builtin_amdgcn_mfma_f32_16x16x32_bf16(ahi, bhi[ds], acc1, 0, 0, 0);
                    acc1 = __builtin_amdgcn_mfma_f32_16x16x32_bf16(ahi, blo[ds], acc1, 0, 0, 0);
                    acc1 = __builtin_amdgcn_mfma_f32_16x16x32_bf16(alo, bhi[ds], acc1, 0, 0, 0);
                } else {
                    acc0 = __builtin_amdgcn_mfma_f32_16x16x32_bf16(ahi, bhi[ds], acc0, 0, 0, 0);
                    acc0 = __builtin_amdgcn_mfma_f32_16x16x32_bf16(ahi, blo[ds], acc0, 0, 0, 0);
                    acc0 = __builtin_amdgcn_mfma_f32_16x16x32_bf16(alo, bhi[ds], acc0, 0, 0, 0);
                }
            }
            const int kb = kt * 16 + g * 4;        // codes this lane scored
            #pragma unroll
            for (int r = 0; r < 4; ++r) {          // k-ascending, strict <
                float s = fmaf(-2.f, __fadd_rn(acc0[r], acc1[r]), w2[kb + r]);
                if (s < b1v)      { b2v = b1v; b1v = s; b1i = kb + r; }
                else if (s < b2v) { b2v = s; }
            }
            __syncthreads();
        }
    }

    // ---- phase 3: merge top-2 across the 4 code-groups (tie-break by index) --
    {
        float v1 = b1v, v2 = b2v; int i1 = b1i;
        #pragma unroll
        for (int m = 16; m < 64; m <<= 1) {
            float o1 = __shfl_xor(v1, m, 64);
            float o2 = __shfl_xor(v2, m, 64);
            int   oi = __shfl_xor(i1, m, 64);
            bool better = (o1 < v1) || (o1 == v1 && oi < i1);
            float nb2 = better ? fminf(v1, o2) : fminf(o1, v2);
            if (better) { v1 = o1; i1 = oi; }
            v2 = nb2;
        }
        if ((lane >> 4) == 0) {
            idx_s[tw - t0] = i1;
            idx_out[tw] = (float)i1;
            if (v2 - v1 <= margin) {               // near-tie: exact rescore
                int p = atomicAdd(amb_cnt, 1);
                amb_list[p] = tw;
            }
        }
    }
    __syncthreads();

    // ---- phase 4: gather q = W[idx] + commitment-loss partial ----
    float lp = 0.f;
    for (int i = tid; i < 64 * (D / 4); i += 256) {
        int d4 = i % (D / 4);
        int t  = i / (D / 4);
        int k  = idx_s[t];
        const float4 w = *(const float4*)(W + (size_t)k * D + d4 * 4);
        const float4 x = *(const float4*)(X + (size_t)(t0 + t) * D + d4 * 4);
        *(float4*)(q_out + (size_t)(t0 + t) * D + d4 * 4) = w;
        float dx;
        dx = w.x - x.x; lp = fmaf(dx, dx, lp);
        dx = w.y - x.y; lp = fmaf(dx, dx, lp);
        dx = w.z - x.z; lp = fmaf(dx, dx, lp);
        dx = w.w - x.w; lp = fmaf(dx, dx, lp);
    }
    #pragma unroll
    for (int off = 32; off > 0; off >>= 1) lp += __shfl_down(lp, off, 64);
    if ((tid & 63) == 0) lred[tid >> 6] = lp;
    __syncthreads();
    if (tid == 0) {
        float tot = (lred[0] + lred[1]) + (lred[2] + lred[3]);
        atomicAdd(loss_out, tot * inv_nd);
    }
}

// ---- exact rescore of ambiguous tokens (validated R4 path) ----
template <int D, int K>
__global__ __launch_bounds__(256)
void cleanup_kernel(const float* __restrict__ X, const float* __restrict__ W,
                    const float* __restrict__ w2, const float* __restrict__ x2,
                    float* __restrict__ q_out, float* __restrict__ idx_out,
                    float* __restrict__ loss_out,
                    const int* __restrict__ cnt, const int* __restrict__ list,
                    float inv_nd)
{
    constexpr int CPL = K / 64;
    const int n    = *cnt;
    const int gw   = (blockIdx.x * 256 + threadIdx.x) >> 6;
    const int lane = threadIdx.x & 63;
    const int nw   = (gridDim.x * 256) >> 6;

    for (int e = gw; e < n; e += nw) {
        const int t = list[e];
        const float* xr = X + (size_t)t * D;
        double acc[CPL];
        #pragma unroll
        for (int c = 0; c < CPL; ++c) {
            const float* wr = W + (size_t)(lane + (c << 6)) * D;
            double a = 0.0;
            for (int d4 = 0; d4 < D / 4; ++d4) {
                const float4 wvv = *(const float4*)(wr + d4 * 4);
                const float4 xv  = *(const float4*)(xr + d4 * 4);
                a = fma((double)xv.x, (double)wvv.x, a);
                a = fma((double)xv.y, (double)wvv.y, a);
                a = fma((double)xv.z, (double)wvv.z, a);
                a = fma((double)xv.w, (double)wvv.w, a);
            }
            acc[c] = a;
        }
        const float x2t = x2[t];
        float bv = FLT_MAX; int bk = 0x7fffffff;
        #pragma unroll
        for (int c = 0; c < CPL; ++c) {
            const int k = lane + (c << 6);
            const float m = (float)acc[c];                   // fl32(dot)
            const float s = __fsub_rn(__fadd_rn(x2t, w2[k]), __fmul_rn(2.0f, m));
            if (s < bv || (s == bv && k < bk)) { bv = s; bk = k; }
        }
        for (int off = 32; off; off >>= 1) {
            const float ov = __shfl_down(bv, off, 64);
            const int   ok = __shfl_down(bk, off, 64);
            if (ov < bv || (ov == bv && ok < bk)) { bv = ov; bk = ok; }
        }
        bk = __shfl(bk, 0, 64);
        const int oldk = (int)idx_out[t];
        if (bk != oldk) {
            if (lane == 0) idx_out[t] = (float)bk;
            const float* wn = W + (size_t)bk * D;
            const float* wo = W + (size_t)oldk * D;
            float dl = 0.f;
            for (int d = lane; d < D; d += 64) {
                const float xv = xr[d], a = wn[d], b = wo[d];
                q_out[(size_t)t * D + d] = a;
                const float da = a - xv, db = b - xv;
                dl += da * da - db * db;
            }
            for (int off = 32; off; off >>= 1) dl += __shfl_down(dl, off, 64);
            if (lane == 0) atomicAdd(loss_out, dl * inv_nd);
        }
    }
}

extern "C" void kernel_launch(void* const* d_in, const int* in_sizes, int n_in,
                              void* d_out, int out_size, void* d_ws, size_t ws_size,
                              hipStream_t stream)
{
    const float* x_hand = (const float*)d_in[0];
    const float* W_hand = (const float*)d_in[1];
    const float* x_loc  = (const float*)d_in[2];
    const float* W_loc  = (const float*)d_in[3];
    const float* x_ori  = (const float*)d_in[4];
    const float* W_ori  = (const float*)d_in[5];
    const float* x_mov  = (const float*)d_in[6];
    const float* W_mov  = (const float*)d_in[7];
    const float* x_nmf  = (const float*)d_in[8];
    const float* W_nmf  = (const float*)d_in[9];

    float* out = (float*)d_out;
    float* q_hand = out;
    float* q_loc  = out + 8388608;
    float* q_ori  = out + 12582912;
    float* q_mov  = out + 14680064;
    float* q_nmf  = out + 18874368;
    float* i_hand = out + 20971520;
    float* i_loc  = out + 21004288;
    float* i_ori  = out + 21037056;
    float* i_mov  = out + 21069824;
    float* i_nmf  = out + 21102592;
    float* loss   = out + 21135360;

    unsigned char* wsb = (unsigned char*)d_ws;
    float* w2b = (float*)(wsb + WSB_W2);
    float* w2_hand = w2b, *w2_loc = w2b + 512, *w2_ori = w2b + 768,
         * w2_mov = w2b + 896, *w2_nmf = w2b + 1152;
    float* x2b = (float*)(wsb + WSB_X2);
    int*   cnt = (int*)(wsb + WSB_CNT);
    int*   lst = (int*)(wsb + WSB_LIST);
    unsigned char* wsp_hand = wsb + WSB_WSP;            // 512*256*2*2 = 524288
    unsigned char* wsp_loc  = wsp_hand + 524288;        // 131072
    unsigned char* wsp_ori  = wsp_loc + 131072;         // 32768
    unsigned char* wsp_mov  = wsp_ori + 32768;          // 131072
    unsigned char* wsp_nmf  = wsp_mov + 131072;         // 32768

    hipMemsetAsync(loss, 0, sizeof(float), stream);
    hipMemsetAsync(cnt, 0, 5 * sizeof(int), stream);

    w2_kernel<<<2, 256, 0, stream>>>(W_hand, w2_hand, 512, 256);
    w2_kernel<<<1, 256, 0, stream>>>(W_loc,  w2_loc,  256, 128);
    w2_kernel<<<1, 256, 0, stream>>>(W_ori,  w2_ori,  128, 64);
    w2_kernel<<<1, 256, 0, stream>>>(W_mov,  w2_mov,  256, 128);
    w2_kernel<<<1, 256, 0, stream>>>(W_nmf,  w2_nmf,  128, 64);

    wsplit_kernel<<<256, 256, 0, stream>>>(W_hand, wsp_hand, 512, 256);
    wsplit_kernel<<<64,  256, 0, stream>>>(W_loc,  wsp_loc,  256, 128);
    wsplit_kernel<<<16,  256, 0, stream>>>(W_ori,  wsp_ori,  128, 64);
    wsplit_kernel<<<64,  256, 0, stream>>>(W_mov,  wsp_mov,  256, 128);
    wsplit_kernel<<<16,  256, 0, stream>>>(W_nmf,  wsp_nmf,  128, 64);

    // margin = D*5e-7 + 1.5e-5 (2x slack over np fp32 quantization + split err)
    vq_mfma<256, 512><<<NTOK / 64, 256, 0, stream>>>(
        x_hand, W_hand, wsp_hand, w2_hand, q_hand, i_hand, loss,
        x2b + 0 * NTOK, cnt + 0, lst + 0 * NTOK,
        1.0f / (32768.0f * 256.0f), 256 * 5e-7f + 1.5e-5f);
    cleanup_kernel<256, 512><<<64, 256, 0, stream>>>(
        x_hand, W_hand, w2_hand, x2b + 0 * NTOK, q_hand, i_hand, loss,
        cnt + 0, lst + 0 * NTOK, 1.0f / (32768.0f * 256.0f));

    vq_mfma<128, 256><<<NTOK / 64, 256, 0, stream>>>(
        x_loc, W_loc, wsp_loc, w2_loc, q_loc, i_loc, loss,
        x2b + 1 * NTOK, cnt + 1, lst + 1 * NTOK,
        1.0f / (32768.0f * 128.0f), 128 * 5e-7f + 1.5e-5f);
    cleanup_kernel<128, 256><<<64, 256, 0, stream>>>(
        x_loc, W_loc, w2_loc, x2b + 1 * NTOK, q_loc, i_loc, loss,
        cnt + 1, lst + 1 * NTOK, 1.0f / (32768.0f * 128.0f));

    vq_mfma<64, 128><<<NTOK / 64, 256, 0, stream>>>(
        x_ori, W_ori, wsp_ori, w2_ori, q_ori, i_ori, loss,
        x2b + 2 * NTOK, cnt + 2, lst + 2 * NTOK,
        1.0f / (32768.0f * 64.0f), 64 * 5e-7f + 1.5e-5f);
    cleanup_kernel<64, 128><<<64, 256, 0, stream>>>(
        x_ori, W_ori, w2_ori, x2b + 2 * NTOK, q_ori, i_ori, loss,
        cnt + 2, lst + 2 * NTOK, 1.0f / (32768.0f * 64.0f));

    vq_mfma<128, 256><<<NTOK / 64, 256, 0, stream>>>(
        x_mov, W_mov, wsp_mov, w2_mov, q_mov, i_mov, loss,
        x2b + 3 * NTOK, cnt + 3, lst + 3 * NTOK,
        1.0f / (32768.0f * 128.0f), 128 * 5e-7f + 1.5e-5f);
    cleanup_kernel<128, 256><<<64, 256, 0, stream>>>(
        x_mov, W_mov, w2_mov, x2b + 3 * NTOK, q_mov, i_mov, loss,
        cnt + 3, lst + 3 * NTOK, 1.0f / (32768.0f * 128.0f));

    vq_mfma<64, 128><<<NTOK / 64, 256, 0, stream>>>(
        x_nmf, W_nmf, wsp_nmf, w2_nmf, q_nmf, i_nmf, loss,
        x2b + 4 * NTOK, cnt + 4, lst + 4 * NTOK,
        1.0f / (32768.0f * 64.0f), 64 * 5e-7f + 1.5e-5f);
    cleanup_kernel<64, 128><<<64, 256, 0, stream>>>(
        x_nmf, W_nmf, w2_nmf, x2b + 4 * NTOK, q_nmf, i_nmf, loss,
        cnt + 4, lst + 4 * NTOK, 1.0f / (32768.0f * 64.0f));
}

// Round 6
// 348.709 us; speedup vs baseline: 1.7077x; 1.1936x over previous
//
#include <hip/hip_runtime.h>
#include <float.h>

#define NTOK 32768  // 16 * 2048 tokens per modality

typedef __attribute__((ext_vector_type(8))) short bf16x8;
typedef __attribute__((ext_vector_type(4))) float f32x4;

// ---- ws byte layout ----
#define WSB_W2    0          // 1280 floats
#define WSB_X2    8192       // 5*NTOK floats (655360 B)
#define WSB_CNT   663808     // 5 ints
#define WSB_LIST  664064     // 5*NTOK ints (655360 B)
#define WSB_WSP   1572864    // swizzled bf16 hi/lo planes (852 KB)

#define GLOAD16(g, l)                                                        \
  __builtin_amdgcn_global_load_lds(                                          \
      (__attribute__((address_space(1))) const void*)(const void*)(g),       \
      (__attribute__((address_space(3))) void*)(void*)(l), 16, 0, 0)

__device__ __forceinline__ unsigned short f2bf(float f) {
    unsigned u = __float_as_uint(f);
    return (unsigned short)((u + 0x7FFFu + ((u >> 16) & 1u)) >> 16);
}
__device__ __forceinline__ float bf2f(unsigned short h) {
    return __uint_as_float(((unsigned)h) << 16);
}

// ================= numpy pairwise-sum replica (fp32) for ||w||^2 ============
__device__ __forceinline__ float pw_sq_block_g(const float* __restrict__ a, int n) {
    float r[8];
    #pragma unroll
    for (int j = 0; j < 8; ++j) r[j] = __fmul_rn(a[j], a[j]);
    for (int i = 8; i < n; i += 8)
        #pragma unroll
        for (int j = 0; j < 8; ++j)
            r[j] = __fadd_rn(r[j], __fmul_rn(a[i + j], a[i + j]));
    return __fadd_rn(__fadd_rn(__fadd_rn(r[0], r[1]), __fadd_rn(r[2], r[3])),
                     __fadd_rn(__fadd_rn(r[4], r[5]), __fadd_rn(r[6], r[7])));
}

__global__ void w2_kernel(const float* __restrict__ W, float* __restrict__ w2,
                          int K, int D) {
    int k = blockIdx.x * blockDim.x + threadIdx.x;
    if (k >= K) return;
    const float* row = W + (size_t)k * D;
    float s = (D > 128)
        ? __fadd_rn(pw_sq_block_g(row, 128), pw_sq_block_g(row + 128, D - 128))
        : pw_sq_block_g(row, D);
    w2[k] = s;
}

// ---- split W into bf16 hi/lo planes, pre-swizzled per 16-code tile ----
__global__ void wsplit_kernel(const float* __restrict__ W,
                              unsigned char* __restrict__ dst, int K, int D) {
    int i = blockIdx.x * 256 + threadIdx.x;  // element-pair index
    if (i >= K * D / 2) return;
    int k  = i / (D / 2);
    int d2 = i % (D / 2);
    float2 v = *(const float2*)(W + (size_t)k * D + 2 * d2);
    unsigned short h0 = f2bf(v.x), h1 = f2bf(v.y);
    unsigned short l0 = f2bf(__fsub_rn(v.x, bf2f(h0)));
    unsigned short l1 = f2bf(__fsub_rn(v.y, bf2f(h1)));
    int tileb = 16 * D * 2;
    int o  = (k & 15) * (D * 2) + d2 * 4;
    int os = o ^ ((k & 7) << 4);             // XOR swizzle (read side matches)
    size_t tb = (size_t)(k >> 4) * (2 * (size_t)tileb);
    *(unsigned int*)(dst + tb + os)         = (unsigned)h0 | ((unsigned)h1 << 16);
    *(unsigned int*)(dst + tb + tileb + os) = (unsigned)l0 | ((unsigned)l1 << 16);
}

// ---- MFMA bf16-split screen: top-2 argmin + gather + loss ----
template <int D, int K>
__global__ __launch_bounds__(256)
void vq_mfma(const float* __restrict__ X, const float* __restrict__ W,
             const unsigned char* __restrict__ Wsp, const float* __restrict__ w2,
             float* __restrict__ q_out, float* __restrict__ idx_out,
             float* __restrict__ loss_out, float* __restrict__ x2_save,
             int* __restrict__ amb_cnt, int* __restrict__ amb_list,
             float inv_nd)
{
    constexpr int DS    = D / 32;       // MFMA K-steps
    constexpr int NT    = K / 16;       // code tiles
    constexpr int TILEB = 16 * D * 2;   // bytes per plane-tile
    constexpr int STG   = (2 * TILEB) / 4096;  // gload16 iters (256 thr)

    __shared__ __align__(16) unsigned char lds[2 * 2 * TILEB];  // [buf][plane]
    __shared__ int   idx_s[64];
    __shared__ float lred[4];

    const int tid  = threadIdx.x;
    const int lane = tid & 63;
    const int wv   = tid >> 6;
    const int t0   = blockIdx.x * 64;
    const int tw   = t0 + wv * 16 + (lane & 15);   // this lane's token

    // ---- phase 0: numpy-pairwise ||x||^2 (exact replica, lane-split tree) ----
    float x2v;
    {
        const float* xr = X + (size_t)tw * D;
        const int jg = lane >> 4;                  // j-pair group 0..3
        constexpr int B1M = (D > 128) ? 16 : (D / 8);
        float2 v = *(const float2*)(xr + 2 * jg);
        float r0 = __fmul_rn(v.x, v.x), r1 = __fmul_rn(v.y, v.y);
        #pragma unroll
        for (int m = 1; m < B1M; ++m) {
            float2 u = *(const float2*)(xr + 8 * m + 2 * jg);
            r0 = __fadd_rn(r0, __fmul_rn(u.x, u.x));
            r1 = __fadd_rn(r1, __fmul_rn(u.y, u.y));
        }
        float p = __fadd_rn(r0, r1);               // r[2jg]+r[2jg+1]
        p = __fadd_rn(p, __shfl_xor(p, 16, 64));   // (r0+r1)+(r2+r3) | (r4..r7)
        p = __fadd_rn(p, __shfl_xor(p, 32, 64));   // full np combine tree
        x2v = p;
        if (D > 128) {                             // second 128-block (D=256)
            float2 w0 = *(const float2*)(xr + 128 + 2 * jg);
            float s0 = __fmul_rn(w0.x, w0.x), s1 = __fmul_rn(w0.y, w0.y);
            #pragma unroll
            for (int m = 1; m < 16; ++m) {
                float2 u = *(const float2*)(xr + 128 + 8 * m + 2 * jg);
                s0 = __fadd_rn(s0, __fmul_rn(u.x, u.x));
                s1 = __fadd_rn(s1, __fmul_rn(u.y, u.y));
            }
            float q2 = __fadd_rn(s0, s1);
            q2 = __fadd_rn(q2, __shfl_xor(q2, 16, 64));
            q2 = __fadd_rn(q2, __shfl_xor(q2, 32, 64));
            x2v = __fadd_rn(p, q2);
        }
        if ((lane >> 4) == 0) x2_save[tw] = x2v;
    }

    // ---- phase 1: X B-fragments (bf16 hi/lo) into registers ----
    bf16x8 bhi[DS], blo[DS];
    {
        const float* xr = X + (size_t)tw * D + (lane >> 4) * 8;
        #pragma unroll
        for (int ds = 0; ds < DS; ++ds) {
            float4 a = *(const float4*)(xr + ds * 32);
            float4 b = *(const float4*)(xr + ds * 32 + 4);
            float f[8] = {a.x, a.y, a.z, a.w, b.x, b.y, b.z, b.w};
            bf16x8 h, l;
            #pragma unroll
            for (int j = 0; j < 8; ++j) {
                unsigned short hh = f2bf(f[j]);
                h[j] = (short)hh;
                l[j] = (short)f2bf(__fsub_rn(f[j], bf2f(hh)));
            }
            bhi[ds] = h; blo[ds] = l;
        }
    }

    // ---- phase 2: k-loop, double-buffered W tiles, 3-way split MFMA ----
    float b1v = FLT_MAX, b2v = FLT_MAX;
    int   b1i = 0;
    {
        const int row   = lane & 15;               // code within tile
        const int g     = lane >> 4;
        const int abase = row * (D * 2);
        const int sw    = (row & 7) << 4;
        #pragma unroll
        for (int s = 0; s < STG; ++s)
            GLOAD16(Wsp + tid * 16 + s * 4096, lds + tid * 16 + s * 4096);
        __syncthreads();

        for (int kt = 0; kt < NT; ++kt) {
            const int cur = kt & 1;
            if (kt + 1 < NT) {                     // prefetch next tile
                const unsigned char* src = Wsp + (size_t)(kt + 1) * (2 * TILEB);
                unsigned char* dl = lds + (cur ^ 1) * (2 * TILEB);
                #pragma unroll
                for (int s = 0; s < STG; ++s)
                    GLOAD16(src + tid * 16 + s * 4096, dl + tid * 16 + s * 4096);
            }
            const unsigned char* base = lds + cur * (2 * TILEB);
            f32x4 acc0 = {0.f, 0.f, 0.f, 0.f}, acc1 = {0.f, 0.f, 0.f, 0.f};
            #pragma unroll
            for (int ds = 0; ds < DS; ++ds) {
                const int off = (abase + ds * 64 + g * 16) ^ sw;
                bf16x8 ahi = *(const bf16x8*)(base + off);
                bf16x8 alo = *(const bf16x8*)(base + TILEB + off);
                if (ds & 1) {                      // two independent acc chains
                    acc1 = __builtin_amdgcn_mfma_f32_16x16x32_bf16(ahi, bhi[ds], acc1, 0, 0, 0);
                    acc1 = __builtin_amdgcn_mfma_f32_16x16x32_bf16(ahi, blo[ds], acc1, 0, 0, 0);
                    acc1 = __builtin_amdgcn_mfma_f32_16x16x32_bf16(alo, bhi[ds], acc1, 0, 0, 0);
                } else {
                    acc0 = __builtin_amdgcn_mfma_f32_16x16x32_bf16(ahi, bhi[ds], acc0, 0, 0, 0);
                    acc0 = __builtin_amdgcn_mfma_f32_16x16x32_bf16(ahi, blo[ds], acc0, 0, 0, 0);
                    acc0 = __builtin_amdgcn_mfma_f32_16x16x32_bf16(alo, bhi[ds], acc0, 0, 0, 0);
                }
            }
            const int kb = kt * 16 + g * 4;        // codes this lane scored
            #pragma unroll
            for (int r = 0; r < 4; ++r) {          // k-ascending, strict <
                float s = fmaf(-2.f, __fadd_rn(acc0[r], acc1[r]), w2[kb + r]);
                if (s < b1v)      { b2v = b1v; b1v = s; b1i = kb + r; }
                else if (s < b2v) { b2v = s; }
            }
            __syncthreads();
        }
    }

    // ---- phase 3: merge top-2 across the 4 code-groups (tie-break by index) --
    {
        float v1 = b1v, v2 = b2v; int i1 = b1i;
        #pragma unroll
        for (int m = 16; m < 64; m <<= 1) {
            float o1 = __shfl_xor(v1, m, 64);
            float o2 = __shfl_xor(v2, m, 64);
            int   oi = __shfl_xor(i1, m, 64);
            bool better = (o1 < v1) || (o1 == v1 && oi < i1);
            float nb2 = better ? fminf(v1, o2) : fminf(o1, v2);
            if (better) { v1 = o1; i1 = oi; }
            v2 = nb2;
        }
        if ((lane >> 4) == 0) {
            idx_s[tw - t0] = i1;
            idx_out[tw] = (float)i1;
            // per-token margin: np contaminates comparisons by <= 4u*(x2+w2)
            // (u=2^-24); 2.6e-7 = 4u*1.09 headroom; +4e-6 covers screen error
            float margin = fmaf(x2v, 2.6e-7f, 4e-6f);
            if (v2 - v1 <= margin) {               // near-tie: exact rescore
                int p = atomicAdd(amb_cnt, 1);
                amb_list[p] = tw;
            }
        }
    }
    __syncthreads();

    // ---- phase 4: gather q = W[idx] + commitment-loss partial ----
    float lp = 0.f;
    for (int i = tid; i < 64 * (D / 4); i += 256) {
        int d4 = i % (D / 4);
        int t  = i / (D / 4);
        int k  = idx_s[t];
        const float4 w = *(const float4*)(W + (size_t)k * D + d4 * 4);
        const float4 x = *(const float4*)(X + (size_t)(t0 + t) * D + d4 * 4);
        *(float4*)(q_out + (size_t)(t0 + t) * D + d4 * 4) = w;
        float dx;
        dx = w.x - x.x; lp = fmaf(dx, dx, lp);
        dx = w.y - x.y; lp = fmaf(dx, dx, lp);
        dx = w.z - x.z; lp = fmaf(dx, dx, lp);
        dx = w.w - x.w; lp = fmaf(dx, dx, lp);
    }
    #pragma unroll
    for (int off = 32; off > 0; off >>= 1) lp += __shfl_down(lp, off, 64);
    if ((tid & 63) == 0) lred[tid >> 6] = lp;
    __syncthreads();
    if (tid == 0) {
        float tot = (lred[0] + lred[1]) + (lred[2] + lred[3]);
        atomicAdd(loss_out, tot * inv_nd);
    }
}

// ---- exact rescore of ambiguous tokens; throughput-shaped (1 token/wave) ----
template <int D, int K>
__global__ __launch_bounds__(256)
void cleanup_kernel(const float* __restrict__ X, const float* __restrict__ W,
                    const float* __restrict__ w2, const float* __restrict__ x2,
                    float* __restrict__ q_out, float* __restrict__ idx_out,
                    float* __restrict__ loss_out,
                    const int* __restrict__ cnt, const int* __restrict__ list,
                    float inv_nd)
{
    constexpr int CPL = K / 64;       // codes per lane
    const int n    = *cnt;
    const int gw   = (blockIdx.x * 256 + threadIdx.x) >> 6;
    const int lane = threadIdx.x & 63;
    const int nw   = (gridDim.x * 256) >> 6;

    for (int e = gw; e < n; e += nw) {
        const int t = list[e];
        const float* xr = X + (size_t)t * D;
        double acc[CPL];
        #pragma unroll
        for (int c = 0; c < CPL; ++c) {
            const float* wr = W + (size_t)(lane + (c << 6)) * D;
            double a0 = 0.0, a1 = 0.0;             // dual chains (latency/2)
            for (int d8 = 0; d8 < D / 8; ++d8) {
                const float4 w0 = *(const float4*)(wr + d8 * 8);
                const float4 w1 = *(const float4*)(wr + d8 * 8 + 4);
                const float4 x0 = *(const float4*)(xr + d8 * 8);
                const float4 x1 = *(const float4*)(xr + d8 * 8 + 4);
                a0 = fma((double)x0.x, (double)w0.x, a0);
                a0 = fma((double)x0.y, (double)w0.y, a0);
                a0 = fma((double)x0.z, (double)w0.z, a0);
                a0 = fma((double)x0.w, (double)w0.w, a0);
                a1 = fma((double)x1.x, (double)w1.x, a1);
                a1 = fma((double)x1.y, (double)w1.y, a1);
                a1 = fma((double)x1.z, (double)w1.z, a1);
                a1 = fma((double)x1.w, (double)w1.w, a1);
            }
            acc[c] = a0 + a1;
        }
        const float x2t = x2[t];
        float bv = FLT_MAX; int bk = 0x7fffffff;
        #pragma unroll
        for (int c = 0; c < CPL; ++c) {
            const int k = lane + (c << 6);
            const float m = (float)acc[c];                   // fl32(dot)
            const float s = __fsub_rn(__fadd_rn(x2t, w2[k]), __fmul_rn(2.0f, m));
            if (s < bv || (s == bv && k < bk)) { bv = s; bk = k; }
        }
        for (int off = 32; off; off >>= 1) {
            const float ov = __shfl_down(bv, off, 64);
            const int   ok = __shfl_down(bk, off, 64);
            if (ov < bv || (ov == bv && ok < bk)) { bv = ov; bk = ok; }
        }
        bk = __shfl(bk, 0, 64);
        const int oldk = (int)idx_out[t];
        if (bk != oldk) {
            if (lane == 0) idx_out[t] = (float)bk;
            const float* wn = W + (size_t)bk * D;
            const float* wo = W + (size_t)oldk * D;
            float dl = 0.f;
            for (int d = lane; d < D; d += 64) {
                const float xv = xr[d], a = wn[d], b = wo[d];
                q_out[(size_t)t * D + d] = a;
                const float da = a - xv, db = b - xv;
                dl += da * da - db * db;
            }
            for (int off = 32; off; off >>= 1) dl += __shfl_down(dl, off, 64);
            if (lane == 0) atomicAdd(loss_out, dl * inv_nd);
        }
    }
}

extern "C" void kernel_launch(void* const* d_in, const int* in_sizes, int n_in,
                              void* d_out, int out_size, void* d_ws, size_t ws_size,
                              hipStream_t stream)
{
    const float* x_hand = (const float*)d_in[0];
    const float* W_hand = (const float*)d_in[1];
    const float* x_loc  = (const float*)d_in[2];
    const float* W_loc  = (const float*)d_in[3];
    const float* x_ori  = (const float*)d_in[4];
    const float* W_ori  = (const float*)d_in[5];
    const float* x_mov  = (const float*)d_in[6];
    const float* W_mov  = (const float*)d_in[7];
    const float* x_nmf  = (const float*)d_in[8];
    const float* W_nmf  = (const float*)d_in[9];

    float* out = (float*)d_out;
    float* q_hand = out;
    float* q_loc  = out + 8388608;
    float* q_ori  = out + 12582912;
    float* q_mov  = out + 14680064;
    float* q_nmf  = out + 18874368;
    float* i_hand = out + 20971520;
    float* i_loc  = out + 21004288;
    float* i_ori  = out + 21037056;
    float* i_mov  = out + 21069824;
    float* i_nmf  = out + 21102592;
    float* loss   = out + 21135360;

    unsigned char* wsb = (unsigned char*)d_ws;
    float* w2b = (float*)(wsb + WSB_W2);
    float* w2_hand = w2b, *w2_loc = w2b + 512, *w2_ori = w2b + 768,
         * w2_mov = w2b + 896, *w2_nmf = w2b + 1152;
    float* x2b = (float*)(wsb + WSB_X2);
    int*   cnt = (int*)(wsb + WSB_CNT);
    int*   lst = (int*)(wsb + WSB_LIST);
    unsigned char* wsp_hand = wsb + WSB_WSP;            // 512*256*2*2 = 524288
    unsigned char* wsp_loc  = wsp_hand + 524288;        // 131072
    unsigned char* wsp_ori  = wsp_loc + 131072;         // 32768
    unsigned char* wsp_mov  = wsp_ori + 32768;          // 131072
    unsigned char* wsp_nmf  = wsp_mov + 131072;         // 32768

    hipMemsetAsync(loss, 0, sizeof(float), stream);
    hipMemsetAsync(cnt, 0, 5 * sizeof(int), stream);

    w2_kernel<<<2, 256, 0, stream>>>(W_hand, w2_hand, 512, 256);
    w2_kernel<<<1, 256, 0, stream>>>(W_loc,  w2_loc,  256, 128);
    w2_kernel<<<1, 256, 0, stream>>>(W_ori,  w2_ori,  128, 64);
    w2_kernel<<<1, 256, 0, stream>>>(W_mov,  w2_mov,  256, 128);
    w2_kernel<<<1, 256, 0, stream>>>(W_nmf,  w2_nmf,  128, 64);

    wsplit_kernel<<<256, 256, 0, stream>>>(W_hand, wsp_hand, 512, 256);
    wsplit_kernel<<<64,  256, 0, stream>>>(W_loc,  wsp_loc,  256, 128);
    wsplit_kernel<<<16,  256, 0, stream>>>(W_ori,  wsp_ori,  128, 64);
    wsplit_kernel<<<64,  256, 0, stream>>>(W_mov,  wsp_mov,  256, 128);
    wsplit_kernel<<<16,  256, 0, stream>>>(W_nmf,  wsp_nmf,  128, 64);

    vq_mfma<256, 512><<<NTOK / 64, 256, 0, stream>>>(
        x_hand, W_hand, wsp_hand, w2_hand, q_hand, i_hand, loss,
        x2b + 0 * NTOK, cnt + 0, lst + 0 * NTOK, 1.0f / (32768.0f * 256.0f));
    cleanup_kernel<256, 512><<<1024, 256, 0, stream>>>(
        x_hand, W_hand, w2_hand, x2b + 0 * NTOK, q_hand, i_hand, loss,
        cnt + 0, lst + 0 * NTOK, 1.0f / (32768.0f * 256.0f));

    vq_mfma<128, 256><<<NTOK / 64, 256, 0, stream>>>(
        x_loc, W_loc, wsp_loc, w2_loc, q_loc, i_loc, loss,
        x2b + 1 * NTOK, cnt + 1, lst + 1 * NTOK, 1.0f / (32768.0f * 128.0f));
    cleanup_kernel<128, 256><<<1024, 256, 0, stream>>>(
        x_loc, W_loc, w2_loc, x2b + 1 * NTOK, q_loc, i_loc, loss,
        cnt + 1, lst + 1 * NTOK, 1.0f / (32768.0f * 128.0f));

    vq_mfma<64, 128><<<NTOK / 64, 256, 0, stream>>>(
        x_ori, W_ori, wsp_ori, w2_ori, q_ori, i_ori, loss,
        x2b + 2 * NTOK, cnt + 2, lst + 2 * NTOK, 1.0f / (32768.0f * 64.0f));
    cleanup_kernel<64, 128><<<1024, 256, 0, stream>>>(
        x_ori, W_ori, w2_ori, x2b + 2 * NTOK, q_ori, i_ori, loss,
        cnt + 2, lst + 2 * NTOK, 1.0f / (32768.0f * 64.0f));

    vq_mfma<128, 256><<<NTOK / 64, 256, 0, stream>>>(
        x_mov, W_mov, wsp_mov, w2_mov, q_mov, i_mov, loss,
        x2b + 3 * NTOK, cnt + 3, lst + 3 * NTOK, 1.0f / (32768.0f * 128.0f));
    cleanup_kernel<128, 256><<<1024, 256, 0, stream>>>(
        x_mov, W_mov, w2_mov, x2b + 3 * NTOK, q_mov, i_mov, loss,
        cnt + 3, lst + 3 * NTOK, 1.0f / (32768.0f * 128.0f));

    vq_mfma<64, 128><<<NTOK / 64, 256, 0, stream>>>(
        x_nmf, W_nmf, wsp_nmf, w2_nmf, q_nmf, i_nmf, loss,
        x2b + 4 * NTOK, cnt + 4, lst + 4 * NTOK, 1.0f / (32768.0f * 64.0f));
    cleanup_kernel<64, 128><<<1024, 256, 0, stream>>>(
        x_nmf, W_nmf, w2_nmf, x2b + 4 * NTOK, q_nmf, i_nmf, loss,
        cnt + 4, lst + 4 * NTOK, 1.0f / (32768.0f * 64.0f));
}